// Round 5
// baseline (70.985 us; speedup 1.0000x reference)
//
#include <hip/hip_runtime.h>

// Segmented mean over sorted segment ids, two-kernel plan (round-3 structure):
//   K1 (boundary pre-pass, int4-vectorized): offs[s] = lower_bound(seg_ids, s)
//       for s in [0, N], computed in O(E) with no searches (ids are sorted).
//   K2 (stream): one wave per 8 consecutive segments. Lanes 0..8 load the 9
//       boundaries from offs (one coalesced L2-hot access), __shfl-broadcast
//       per segment; inner loop = proven unroll-2 float4 stream (lane t:
//       col (t&15)*4 of rows start+(t>>4)+4k), shfl_xor(16|32) fold,
//       lanes 0..15 store one float4 each. Nontemporal value loads (values
//       are single-use; keep L2/L3 for offs + out).
// ws usage: (N+1) ints = 200 KB.

#define SPW 8   // segments per wave
#define WPB 4   // waves per block

typedef float f4 __attribute__((ext_vector_type(4)));

__global__ __launch_bounds__(256) void seg_bounds_kernel(
    const int* __restrict__ seg_ids,
    int*       __restrict__ offs,   // [N+1]
    int E, int N)
{
    const int q    = blockIdx.x * blockDim.x + threadIdx.x;  // quad index
    const int base = q << 2;
    if (base >= E) return;

    int id0, id1, id2, id3;
    int nv = E - base;                       // >=1
    if (nv >= 4) {
        const int4 v = *reinterpret_cast<const int4*>(seg_ids + base);
        id0 = v.x; id1 = v.y; id2 = v.z; id3 = v.w;
    } else {
        id0 = seg_ids[base];
        id1 = (nv > 1) ? seg_ids[base + 1] : id0;
        id2 = (nv > 2) ? seg_ids[base + 2] : id1;
        id3 = id2;
    }

    int prev = (base > 0) ? seg_ids[base - 1] : -1;

    // first row of every segment in (prev, id_j] is base+j
    for (int s = prev + 1; s <= id0; ++s) offs[s] = base + 0;
    if (nv > 1) for (int s = id0 + 1; s <= id1; ++s) offs[s] = base + 1;
    if (nv > 2) for (int s = id1 + 1; s <= id2; ++s) offs[s] = base + 2;
    if (nv > 3) for (int s = id2 + 1; s <= id3; ++s) offs[s] = base + 3;

    if (base + 4 >= E) {                     // last quad fills the tail
        for (int s = id3 + 1; s <= N; ++s) offs[s] = E;
    }
}

__global__ __launch_bounds__(256) void seg_mean_kernel(
    const float* __restrict__ values,
    const int*   __restrict__ offs,
    float*       __restrict__ out,
    int N)
{
    const int wave = threadIdx.x >> 6;
    const int wid  = blockIdx.x * WPB + wave;    // global wave id
    const int sg0  = wid * SPW;                  // first segment of this wave
    if (sg0 >= N) return;

    const int t = threadIdx.x & 63;

    // lanes 0..SPW hold the 9 boundaries offs[sg0 .. sg0+SPW]
    int myoff = 0;
    if (t <= SPW) myoff = offs[min(sg0 + t, N)];

    const int rsub = t >> 4;          // row-in-group-of-4: 0..3
    const int c4   = (t & 15) << 2;   // column base: 0,4,...,60

    const int nseg = min(SPW, N - sg0);
    for (int k = 0; k < nseg; ++k) {
        const int s     = sg0 + k;
        const int start = __shfl(myoff, k, 64);
        const int end   = __shfl(myoff, k + 1, 64);
        const int count = end - start;

        // lane t covers row start+(t>>4)+4j, cols (t&15)*4 .. +3
        const f4* p = reinterpret_cast<const f4*>(
            values + (size_t)start * 64 + (t << 2));

        f4 a0 = {0.f, 0.f, 0.f, 0.f};
        f4 a1 = {0.f, 0.f, 0.f, 0.f};

        int r = start + rsub;
        // unrolled by 2: rows r and r+4 both valid while r+4 < end
        for (; r + 4 < end; r += 8, p += 128) {
            const f4 v0 = __builtin_nontemporal_load(p);
            const f4 v1 = __builtin_nontemporal_load(p + 64);
            a0 += v0;
            a1 += v1;
        }
        if (r < end) {
            a0 += __builtin_nontemporal_load(p);
        }
        a0 += a1;

        // fold the 4 row-subgroups (lanes differing in bits 4,5 share columns)
        a0.x += __shfl_xor(a0.x, 16, 64);
        a0.y += __shfl_xor(a0.y, 16, 64);
        a0.z += __shfl_xor(a0.z, 16, 64);
        a0.w += __shfl_xor(a0.w, 16, 64);
        a0.x += __shfl_xor(a0.x, 32, 64);
        a0.y += __shfl_xor(a0.y, 32, 64);
        a0.z += __shfl_xor(a0.z, 32, 64);
        a0.w += __shfl_xor(a0.w, 32, 64);

        if (t < 16) {
            const float inv = (count > 0) ? (1.0f / (float)count) : 0.0f;
            f4 o = a0 * inv;
            *reinterpret_cast<f4*>(out + (size_t)s * 64 + c4) = o;
        }
    }
}

extern "C" void kernel_launch(void* const* d_in, const int* in_sizes, int n_in,
                              void* d_out, int out_size, void* d_ws, size_t ws_size,
                              hipStream_t stream) {
    const float* values  = (const float*)d_in[0];
    const int*   seg_ids = (const int*)d_in[1];
    float*       out     = (float*)d_out;
    int*         offs    = (int*)d_ws;   // (N+1) ints = ~200 KB

    const int E = in_sizes[1];        // number of rows (= len(segment_ids))
    const int N = out_size / 64;      // number of segments (D = 64)

    const int quads  = (E + 3) / 4;
    const int nwaves = (N + SPW - 1) / SPW;
    const int nblk   = (nwaves + WPB - 1) / WPB;

    seg_bounds_kernel<<<dim3((quads + 255) / 256), dim3(256), 0, stream>>>(seg_ids, offs, E, N);
    seg_mean_kernel<<<dim3(nblk), dim3(256), 0, stream>>>(values, offs, out, N);
}

// Round 7
// 70.854 us; speedup vs baseline: 1.0019x; 1.0019x over previous
//
#include <hip/hip_runtime.h>

// Segmented mean over sorted segment ids, two-kernel plan (round-3 lineage):
//   K1 (boundary pre-pass, int4-vectorized): offs[s] = lower_bound(seg_ids, s)
//       for s in [0, N], computed in O(E) with no searches (ids are sorted).
//   K2 (stream): one wave per TWO adjacent segments. Adjacent segments are
//       contiguous rows, so the wave streams ONE contiguous range
//       [offs[s0], offs[s0+2]) with the proven unroll-2 float4 loop (lane t:
//       col (t&15)*4 of rows base+(t>>4)+4k); each row is routed to acc x or
//       y by one per-lane compare (r < offs[s0+1]). Two shfl_xor(16|32)
//       folds; lanes 0..15 store one float4 per segment.
// ws usage: (N+1) ints = 200 KB.

#define WPB 4   // waves per block

typedef float f4 __attribute__((ext_vector_type(4)));

__global__ __launch_bounds__(256) void seg_bounds_kernel(
    const int* __restrict__ seg_ids,
    int*       __restrict__ offs,   // [N+1]
    int E, int N)
{
    const int q    = blockIdx.x * blockDim.x + threadIdx.x;  // quad index
    const int base = q << 2;
    if (base >= E) return;

    int id0, id1, id2, id3;
    int nv = E - base;                       // >=1
    if (nv >= 4) {
        const int4 v = *reinterpret_cast<const int4*>(seg_ids + base);
        id0 = v.x; id1 = v.y; id2 = v.z; id3 = v.w;
    } else {
        id0 = seg_ids[base];
        id1 = (nv > 1) ? seg_ids[base + 1] : id0;
        id2 = (nv > 2) ? seg_ids[base + 2] : id1;
        id3 = id2;
    }

    int prev = (base > 0) ? seg_ids[base - 1] : -1;

    // first row of every segment in (prev, id_j] is base+j
    for (int s = prev + 1; s <= id0; ++s) offs[s] = base + 0;
    if (nv > 1) for (int s = id0 + 1; s <= id1; ++s) offs[s] = base + 1;
    if (nv > 2) for (int s = id1 + 1; s <= id2; ++s) offs[s] = base + 2;
    if (nv > 3) for (int s = id2 + 1; s <= id3; ++s) offs[s] = base + 3;

    if (base + 4 >= E) {                     // last quad fills the tail
        for (int s = id3 + 1; s <= N; ++s) offs[s] = E;
    }
}

__device__ __forceinline__ void fold(f4& a) {
    a.x += __shfl_xor(a.x, 16, 64); a.y += __shfl_xor(a.y, 16, 64);
    a.z += __shfl_xor(a.z, 16, 64); a.w += __shfl_xor(a.w, 16, 64);
    a.x += __shfl_xor(a.x, 32, 64); a.y += __shfl_xor(a.y, 32, 64);
    a.z += __shfl_xor(a.z, 32, 64); a.w += __shfl_xor(a.w, 32, 64);
}

__global__ __launch_bounds__(256) void seg_mean_kernel(
    const float* __restrict__ values,
    const int*   __restrict__ offs,
    float*       __restrict__ out,
    int N)
{
    const int wave = threadIdx.x >> 6;
    const int wid  = blockIdx.x * WPB + wave;    // global wave id
    const int s0   = wid * 2;                    // first of two segments
    if (s0 >= N) return;

    const int t   = threadIdx.x & 63;
    const bool two = (s0 + 1) < N;

    const int b0 = offs[s0];
    const int b1 = offs[s0 + 1];
    const int b2 = two ? offs[s0 + 2] : b1;

    const int rsub = t >> 4;          // row-in-group-of-4: 0..3
    const int c4   = (t & 15) << 2;   // column base: 0,4,...,60

    // stream the contiguous range [b0, b2); route rows by (r < b1)
    const f4* p = reinterpret_cast<const f4*>(
        values + (size_t)b0 * 64 + (t << 2));

    f4 x0 = {0.f,0.f,0.f,0.f}, x1 = {0.f,0.f,0.f,0.f};
    f4 y0 = {0.f,0.f,0.f,0.f}, y1 = {0.f,0.f,0.f,0.f};

    int r = b0 + rsub;
    for (; r + 4 < b2; r += 8, p += 128) {
        const f4 v0 = p[0];
        const f4 v1 = p[64];
        if (r < b1)     x0 += v0; else y0 += v0;
        if (r + 4 < b1) x1 += v1; else y1 += v1;
    }
    if (r < b2) {
        const f4 v0 = p[0];
        if (r < b1) x0 += v0; else y0 += v0;
    }
    x0 += x1;
    y0 += y1;

    fold(x0);
    fold(y0);

    if (t < 16) {
        const int   c0   = b1 - b0;
        const float inv0 = (c0 > 0) ? (1.0f / (float)c0) : 0.0f;
        *reinterpret_cast<f4*>(out + (size_t)s0 * 64 + c4) = x0 * inv0;
        if (two) {
            const int   c1   = b2 - b1;
            const float inv1 = (c1 > 0) ? (1.0f / (float)c1) : 0.0f;
            *reinterpret_cast<f4*>(out + (size_t)(s0 + 1) * 64 + c4) = y0 * inv1;
        }
    }
}

extern "C" void kernel_launch(void* const* d_in, const int* in_sizes, int n_in,
                              void* d_out, int out_size, void* d_ws, size_t ws_size,
                              hipStream_t stream) {
    const float* values  = (const float*)d_in[0];
    const int*   seg_ids = (const int*)d_in[1];
    float*       out     = (float*)d_out;
    int*         offs    = (int*)d_ws;   // (N+1) ints = ~200 KB

    const int E = in_sizes[1];        // rows (= len(segment_ids))
    const int N = out_size / 64;      // segments (D = 64)

    const int quads  = (E + 3) / 4;
    const int nwaves = (N + 1) / 2;
    const int nblk   = (nwaves + WPB - 1) / WPB;

    seg_bounds_kernel<<<dim3((quads + 255) / 256), dim3(256), 0, stream>>>(seg_ids, offs, E, N);
    seg_mean_kernel<<<dim3(nblk), dim3(256), 0, stream>>>(values, offs, out, N);
}

// Round 8
// 65.102 us; speedup vs baseline: 1.0904x; 1.0884x over previous
//
#include <hip/hip_runtime.h>

// Segmented mean over sorted segment ids, two-kernel plan (round-3 lineage):
//   K1 (boundary pre-pass, int4-vectorized): offs[s] = lower_bound(seg_ids, s)
//       for s in [0, N], computed in O(E) with no searches (ids are sorted).
//   K2 (stream): one wave per segment (round-3 mapping — every multi-segment
//       variant regressed). NEW: 8-deep batched loads — per iteration the
//       lane predicated-loads up to 8 float4 groups (rows start+(t>>4)+4k,
//       k=0..7, col (t&15)*4) BEFORE any use, one effective vmcnt stall,
//       tree-sum. Avg segment (25 rows ~ 6.25 groups) = ONE batch, one stall
//       per wave vs ~3 in the unroll-2 loop. shfl_xor(16|32) fold; lanes
//       0..15 store one float4.
// ws usage: (N+1) ints = 200 KB.

#define WPB 4   // waves per block

typedef float f4 __attribute__((ext_vector_type(4)));

__global__ __launch_bounds__(256) void seg_bounds_kernel(
    const int* __restrict__ seg_ids,
    int*       __restrict__ offs,   // [N+1]
    int E, int N)
{
    const int q    = blockIdx.x * blockDim.x + threadIdx.x;  // quad index
    const int base = q << 2;
    if (base >= E) return;

    int id0, id1, id2, id3;
    int nv = E - base;                       // >=1
    if (nv >= 4) {
        const int4 v = *reinterpret_cast<const int4*>(seg_ids + base);
        id0 = v.x; id1 = v.y; id2 = v.z; id3 = v.w;
    } else {
        id0 = seg_ids[base];
        id1 = (nv > 1) ? seg_ids[base + 1] : id0;
        id2 = (nv > 2) ? seg_ids[base + 2] : id1;
        id3 = id2;
    }

    int prev = (base > 0) ? seg_ids[base - 1] : -1;

    // first row of every segment in (prev, id_j] is base+j
    for (int s = prev + 1; s <= id0; ++s) offs[s] = base + 0;
    if (nv > 1) for (int s = id0 + 1; s <= id1; ++s) offs[s] = base + 1;
    if (nv > 2) for (int s = id1 + 1; s <= id2; ++s) offs[s] = base + 2;
    if (nv > 3) for (int s = id2 + 1; s <= id3; ++s) offs[s] = base + 3;

    if (base + 4 >= E) {                     // last quad fills the tail
        for (int s = id3 + 1; s <= N; ++s) offs[s] = E;
    }
}

__global__ __launch_bounds__(256) void seg_mean_kernel(
    const float* __restrict__ values,
    const int*   __restrict__ offs,
    float*       __restrict__ out,
    int N)
{
    const int wave = threadIdx.x >> 6;
    const int s    = blockIdx.x * WPB + wave;    // one segment per wave
    if (s >= N) return;

    const int t = threadIdx.x & 63;

    const int start = offs[s];
    const int end   = offs[s + 1];
    const int count = end - start;

    const int rsub = t >> 4;          // row-in-group-of-4: 0..3
    const int c4   = (t & 15) << 2;   // column base: 0,4,...,60

    // lane t covers rows start+(t>>4)+4k, cols (t&15)*4 .. +3
    const f4* p = reinterpret_cast<const f4*>(
        values + (size_t)start * 64 + (t << 2));

    f4 acc = {0.f, 0.f, 0.f, 0.f};
    int r = start + rsub;

    while (r < end) {
        // batch-issue up to 8 predicated group loads, then one tree-sum.
        f4 v0 = {0.f,0.f,0.f,0.f}, v1 = {0.f,0.f,0.f,0.f};
        f4 v2 = {0.f,0.f,0.f,0.f}, v3 = {0.f,0.f,0.f,0.f};
        f4 v4 = {0.f,0.f,0.f,0.f}, v5 = {0.f,0.f,0.f,0.f};
        f4 v6 = {0.f,0.f,0.f,0.f}, v7 = {0.f,0.f,0.f,0.f};

        v0 = p[0];                            // r < end guaranteed
        if (r +  4 < end) v1 = p[64];
        if (r +  8 < end) v2 = p[128];
        if (r + 12 < end) v3 = p[192];
        if (r + 16 < end) v4 = p[256];
        if (r + 20 < end) v5 = p[320];
        if (r + 24 < end) v6 = p[384];
        if (r + 28 < end) v7 = p[448];

        acc += ((v0 + v1) + (v2 + v3)) + ((v4 + v5) + (v6 + v7));

        r += 32;
        p += 512;
    }

    // fold the 4 row-subgroups (lanes differing in bits 4,5 share columns)
    acc.x += __shfl_xor(acc.x, 16, 64);
    acc.y += __shfl_xor(acc.y, 16, 64);
    acc.z += __shfl_xor(acc.z, 16, 64);
    acc.w += __shfl_xor(acc.w, 16, 64);
    acc.x += __shfl_xor(acc.x, 32, 64);
    acc.y += __shfl_xor(acc.y, 32, 64);
    acc.z += __shfl_xor(acc.z, 32, 64);
    acc.w += __shfl_xor(acc.w, 32, 64);

    if (t < 16) {
        const float inv = (count > 0) ? (1.0f / (float)count) : 0.0f;
        *reinterpret_cast<f4*>(out + (size_t)s * 64 + c4) = acc * inv;
    }
}

extern "C" void kernel_launch(void* const* d_in, const int* in_sizes, int n_in,
                              void* d_out, int out_size, void* d_ws, size_t ws_size,
                              hipStream_t stream) {
    const float* values  = (const float*)d_in[0];
    const int*   seg_ids = (const int*)d_in[1];
    float*       out     = (float*)d_out;
    int*         offs    = (int*)d_ws;   // (N+1) ints = ~200 KB

    const int E = in_sizes[1];        // rows (= len(segment_ids))
    const int N = out_size / 64;      // segments (D = 64)

    const int quads = (E + 3) / 4;
    const int nblk  = (N + WPB - 1) / WPB;

    seg_bounds_kernel<<<dim3((quads + 255) / 256), dim3(256), 0, stream>>>(seg_ids, offs, E, N);
    seg_mean_kernel<<<dim3(nblk), dim3(256), 0, stream>>>(values, offs, out, N);
}

// Round 9
// 63.259 us; speedup vs baseline: 1.1221x; 1.0291x over previous
//
#include <hip/hip_runtime.h>

// Segmented mean over sorted segment ids, two-kernel plan (round-8 winner +
// nontemporal value loads):
//   K1 (boundary pre-pass, int4-vectorized): offs[s] = lower_bound(seg_ids, s)
//       for s in [0, N], computed in O(E) with no searches (ids are sorted).
//   K2 (stream): one wave per segment. 8-deep batched PREDICATED loads (rows
//       start+(t>>4)+4k, k=0..7, col (t&15)*4) issued before any use -> one
//       effective vmcnt stall per avg segment (25 rows ~ 6.25 groups), then
//       tree-sum. Value loads are NONTEMPORAL (values are single-use 320 MB;
//       keep L2/L3 for offs/seg_ids/out). shfl_xor(16|32) fold; lanes 0..15
//       store one float4.
// ws usage: (N+1) ints = 200 KB.

#define WPB 4   // waves per block

typedef float f4 __attribute__((ext_vector_type(4)));

__global__ __launch_bounds__(256) void seg_bounds_kernel(
    const int* __restrict__ seg_ids,
    int*       __restrict__ offs,   // [N+1]
    int E, int N)
{
    const int q    = blockIdx.x * blockDim.x + threadIdx.x;  // quad index
    const int base = q << 2;
    if (base >= E) return;

    int id0, id1, id2, id3;
    int nv = E - base;                       // >=1
    if (nv >= 4) {
        const int4 v = *reinterpret_cast<const int4*>(seg_ids + base);
        id0 = v.x; id1 = v.y; id2 = v.z; id3 = v.w;
    } else {
        id0 = seg_ids[base];
        id1 = (nv > 1) ? seg_ids[base + 1] : id0;
        id2 = (nv > 2) ? seg_ids[base + 2] : id1;
        id3 = id2;
    }

    int prev = (base > 0) ? seg_ids[base - 1] : -1;

    // first row of every segment in (prev, id_j] is base+j
    for (int s = prev + 1; s <= id0; ++s) offs[s] = base + 0;
    if (nv > 1) for (int s = id0 + 1; s <= id1; ++s) offs[s] = base + 1;
    if (nv > 2) for (int s = id1 + 1; s <= id2; ++s) offs[s] = base + 2;
    if (nv > 3) for (int s = id2 + 1; s <= id3; ++s) offs[s] = base + 3;

    if (base + 4 >= E) {                     // last quad fills the tail
        for (int s = id3 + 1; s <= N; ++s) offs[s] = E;
    }
}

__global__ __launch_bounds__(256) void seg_mean_kernel(
    const float* __restrict__ values,
    const int*   __restrict__ offs,
    float*       __restrict__ out,
    int N)
{
    const int wave = threadIdx.x >> 6;
    const int s    = blockIdx.x * WPB + wave;    // one segment per wave
    if (s >= N) return;

    const int t = threadIdx.x & 63;

    const int start = offs[s];
    const int end   = offs[s + 1];
    const int count = end - start;

    const int rsub = t >> 4;          // row-in-group-of-4: 0..3
    const int c4   = (t & 15) << 2;   // column base: 0,4,...,60

    // lane t covers rows start+(t>>4)+4k, cols (t&15)*4 .. +3
    const f4* p = reinterpret_cast<const f4*>(
        values + (size_t)start * 64 + (t << 2));

    f4 acc = {0.f, 0.f, 0.f, 0.f};
    int r = start + rsub;

    while (r < end) {
        // batch-issue up to 8 predicated group loads, then one tree-sum.
        f4 v0 = {0.f,0.f,0.f,0.f}, v1 = {0.f,0.f,0.f,0.f};
        f4 v2 = {0.f,0.f,0.f,0.f}, v3 = {0.f,0.f,0.f,0.f};
        f4 v4 = {0.f,0.f,0.f,0.f}, v5 = {0.f,0.f,0.f,0.f};
        f4 v6 = {0.f,0.f,0.f,0.f}, v7 = {0.f,0.f,0.f,0.f};

        v0 = __builtin_nontemporal_load(p);          // r < end guaranteed
        if (r +  4 < end) v1 = __builtin_nontemporal_load(p +  64);
        if (r +  8 < end) v2 = __builtin_nontemporal_load(p + 128);
        if (r + 12 < end) v3 = __builtin_nontemporal_load(p + 192);
        if (r + 16 < end) v4 = __builtin_nontemporal_load(p + 256);
        if (r + 20 < end) v5 = __builtin_nontemporal_load(p + 320);
        if (r + 24 < end) v6 = __builtin_nontemporal_load(p + 384);
        if (r + 28 < end) v7 = __builtin_nontemporal_load(p + 448);

        acc += ((v0 + v1) + (v2 + v3)) + ((v4 + v5) + (v6 + v7));

        r += 32;
        p += 512;
    }

    // fold the 4 row-subgroups (lanes differing in bits 4,5 share columns)
    acc.x += __shfl_xor(acc.x, 16, 64);
    acc.y += __shfl_xor(acc.y, 16, 64);
    acc.z += __shfl_xor(acc.z, 16, 64);
    acc.w += __shfl_xor(acc.w, 16, 64);
    acc.x += __shfl_xor(acc.x, 32, 64);
    acc.y += __shfl_xor(acc.y, 32, 64);
    acc.z += __shfl_xor(acc.z, 32, 64);
    acc.w += __shfl_xor(acc.w, 32, 64);

    if (t < 16) {
        const float inv = (count > 0) ? (1.0f / (float)count) : 0.0f;
        *reinterpret_cast<f4*>(out + (size_t)s * 64 + c4) = acc * inv;
    }
}

extern "C" void kernel_launch(void* const* d_in, const int* in_sizes, int n_in,
                              void* d_out, int out_size, void* d_ws, size_t ws_size,
                              hipStream_t stream) {
    const float* values  = (const float*)d_in[0];
    const int*   seg_ids = (const int*)d_in[1];
    float*       out     = (float*)d_out;
    int*         offs    = (int*)d_ws;   // (N+1) ints = ~200 KB

    const int E = in_sizes[1];        // rows (= len(segment_ids))
    const int N = out_size / 64;      // segments (D = 64)

    const int quads = (E + 3) / 4;
    const int nblk  = (N + WPB - 1) / WPB;

    seg_bounds_kernel<<<dim3((quads + 255) / 256), dim3(256), 0, stream>>>(seg_ids, offs, E, N);
    seg_mean_kernel<<<dim3(nblk), dim3(256), 0, stream>>>(values, offs, out, N);
}